// Round 8
// baseline (691.877 us; speedup 1.0000x reference)
//
#include <hip/hip_runtime.h>

#define KCODES 4096
#define NROWS  32768
#define DIM    256
#define BM     64
#define BN     256
#define NJG    4
#define NJB    (KCODES / (BN * NJG))   // 4 j-tiles per block

typedef __attribute__((ext_vector_type(8))) short  short8;
typedef __attribute__((ext_vector_type(4))) float  float4v;

__device__ inline unsigned short f2bf(float f) {
    unsigned u = __float_as_uint(f);
    unsigned r = (u >> 16) & 1u;
    return (unsigned short)((u + 0x7FFFu + r) >> 16);   // RNE
}
__device__ inline void load_lds16(const void* g, void* l) {
    __builtin_amdgcn_global_load_lds((const __attribute__((address_space(1))) void*)g,
                                     (__attribute__((address_space(3))) void*)l, 16, 0, 0);
}

// ---------------- kernel 0: fused prep ----------------
// blocks [0,4096): x -> A2 bf16, pre-swizzled K=32-chunk layout
//   A2 slot t = mB*2048 + kt*256 + r*4 + u  holds x[mB*64+r][kt*32 + (u^((r>>1)&3))*8 ..+8]
// blocks [4096,4608): cb -> B2 bf16, same layout per 256-code j-tile
//   B2 slot t = jt*8192 + ks*1024 + r*4 + u holds cb[jt*256+r][ks*32 + (u^((r>>1)&3))*8 ..+8]
// blocks [4608,4624): csq (verbatim fp32 recipe)
__global__ __launch_bounds__(256) void prep_kernel(const float* __restrict__ x,
                                                   const float* __restrict__ cb,
                                                   unsigned short* __restrict__ A2,
                                                   unsigned short* __restrict__ B2,
                                                   float* __restrict__ csq) {
    const int bid = blockIdx.x, tid = threadIdx.x;
    if (bid < 4096) {
        int t = bid * 256 + tid;
        int u = t & 3, r = (t >> 2) & 63, kt = (t >> 8) & 7, mB = t >> 11;
        int klog = kt * 32 + ((u ^ ((r >> 1) & 3)) << 3);
        const float4* xs = (const float4*)(x + (size_t)(mB * 64 + r) * DIM + klog);
        float4 v0 = xs[0], v1 = xs[1];
        unsigned short h[8] = { f2bf(v0.x), f2bf(v0.y), f2bf(v0.z), f2bf(v0.w),
                                f2bf(v1.x), f2bf(v1.y), f2bf(v1.z), f2bf(v1.w) };
        ((short8*)A2)[t] = *(short8*)h;
    } else if (bid < 4608) {
        int t = (bid - 4096) * 256 + tid;
        int u = t & 3, r = (t >> 2) & 255, ks = (t >> 10) & 7, jt = t >> 13;
        int klog = ks * 32 + ((u ^ ((r >> 1) & 3)) << 3);
        const float4* cs = (const float4*)(cb + (size_t)(jt * 256 + r) * DIM + klog);
        float4 v0 = cs[0], v1 = cs[1];
        unsigned short h[8] = { f2bf(v0.x), f2bf(v0.y), f2bf(v0.z), f2bf(v0.w),
                                f2bf(v1.x), f2bf(v1.y), f2bf(v1.z), f2bf(v1.w) };
        ((short8*)B2)[t] = *(short8*)h;
    } else {
        int code = (bid - 4608) * 256 + tid;
        const float4* row = (const float4*)(cb + (size_t)code * DIM);
        float s = 0.f;
        #pragma unroll 8
        for (int i = 0; i < DIM / 4; ++i) {
            float4 v = row[i];
            s += v.x * v.x + v.y * v.y + v.z * v.z + v.w * v.w;
        }
        csq[code] = s;
    }
}

// ---------------- kernel 1: K=256 bf16 GEMM, tri-buffered B, 1 barrier/step ----------------
// BM=64 (sA 32 KB resident, DMA-staged), BN=256 across 4 waves (wave tile 64x64, mi=4 ni=4).
// 32 steps of K=32; stage(t+2) issued AFTER bar(t) (WAR covered by bar); vmcnt(4) counted.
// LDS 32+48=80 KB -> 2 blocks/CU. No launch_bounds: allocator free to use >128 VGPR (R5).
// grid = 2048: jg=(h>>3)&3, mB=(h&7)|((h>>5)<<3)  (4 same-mB jg-blocks share an XCD L2)
__global__ void gemm_top2_kernel(const unsigned short* __restrict__ A2,
                                 const unsigned short* __restrict__ B2,
                                 const float* __restrict__ csq,
                                 float4* __restrict__ pairs) {
    __shared__ unsigned short sA[2048 * 8];      // 32 KB: [kt][r][u] 16B slots
    __shared__ unsigned short sB[3][1024 * 8];   // 3 x 16 KB: [r][u] 16B slots

    const int tid = threadIdx.x;
    const int lane = tid & 63, wn = tid >> 6;
    const int c = lane & 15, q = lane >> 4;
    const int h  = blockIdx.x;
    const int jg = (h >> 3) & 3;
    const int mB = (h & 7) | ((h >> 5) << 3);

    // lane-constant swizzled byte offset within any 1 KB row-quarter
    const int u = q ^ ((c >> 1) & 3);
    const int laneOff = c * 64 + u * 16;
    const char* sAc = (const char*)sA;

    // ---- stage A: 8 x 16B DMA per thread from pre-swizzled A2 ----
    {
        const unsigned short* Ag = A2 + (size_t)mB * 2048 * 8;
        #pragma unroll
        for (int i = 0; i < 8; ++i)
            load_lds16(Ag + (size_t)(i * 256 + tid) * 8, &sA[(size_t)(i * 256 + tid) * 8]);
    }

#define STAGE(T, BUF) do {                                                              \
        const unsigned short* gb = B2 +                                                 \
            (size_t)(((jg * NJB + ((T) >> 3)) * 8 + ((T) & 7))) * 8192;                 \
        _Pragma("unroll")                                                               \
        for (int i_ = 0; i_ < 4; ++i_)                                                  \
            load_lds16(gb + (size_t)(i_ * 256 + tid) * 8,                               \
                       &sB[BUF][(size_t)(i_ * 256 + tid) * 8]);                         \
    } while (0)

#define TOP2(D, K, S) do {                                       \
        bool f1 = (D) < rv1[S];                                  \
        bool f2 = (D) < rv2[S];                                  \
        unsigned p = pk[S];                                      \
        pk[S]  = f1 ? ((p << 16) | (unsigned)(K))                \
                    : (f2 ? (((unsigned)(K) << 16) | (p & 0xFFFFu)) : p); \
        rv2[S] = f1 ? rv1[S] : (f2 ? (D) : rv2[S]);              \
        rv1[S] = f1 ? (D) : rv1[S];                              \
    } while (0)

    float rv1[16], rv2[16]; unsigned pk[16];
    #pragma unroll
    for (int s = 0; s < 16; ++s) { rv1[s] = INFINITY; rv2[s] = INFINITY; pk[s] = 0xFFFFFFFFu; }

    const float* pC = csq + jg * (NJB * BN) + wn * 64 + c;
    const int k0base = jg * (NJB * BN) + wn * 64 + c;

    // ---- prologue: A DMA + first two B chunks in flight ----
    STAGE(0, 0);
    STAGE(1, 1);

    #pragma unroll
    for (int jj = 0; jj < NJB; ++jj) {
        float4v acc[4][4];
        #pragma unroll
        for (int mi = 0; mi < 4; ++mi)
            #pragma unroll
            for (int ni = 0; ni < 4; ++ni)
                #pragma unroll
                for (int e = 0; e < 4; ++e) acc[mi][ni][e] = 0.f;

        #pragma unroll
        for (int kt = 0; kt < 8; ++kt) {
            const int t = jj * 8 + kt;
            // counted wait: chunk t landed (and, via barrier, all waves done reading
            // buf (t+2)%3 at step t-1); newest 4 loads (stage t+1) may stay in flight
            if (t == 31) asm volatile("s_waitcnt vmcnt(0)" ::: "memory");
            else         asm volatile("s_waitcnt vmcnt(4)" ::: "memory");
            __builtin_amdgcn_s_barrier();
            asm volatile("" ::: "memory");

            if (kt != 7 && t + 2 < 32) STAGE(t + 2, (t + 2) % 3);

            const char* bufp = (const char*)sB[t % 3];
            short8 aF[4], bF[4];
            #pragma unroll
            for (int mi = 0; mi < 4; ++mi)
                aF[mi] = *(const short8*)(sAc + kt * 4096 + mi * 1024 + laneOff);
            #pragma unroll
            for (int ni = 0; ni < 4; ++ni)
                bF[ni] = *(const short8*)(bufp + wn * 4096 + ni * 1024 + laneOff);
            #pragma unroll
            for (int mi = 0; mi < 4; ++mi)
                #pragma unroll
                for (int ni = 0; ni < 4; ++ni)
                    acc[mi][ni] = __builtin_amdgcn_mfma_f32_16x16x32_bf16(aF[mi], bF[ni], acc[mi][ni], 0, 0, 0);

            if (kt == 7) {
                // epilogue: csq first, THEN the deferred stage (so the compiler's
                // csq-wait counts the stage loads as newest-4, not a drain)
                float cs[4];
                #pragma unroll
                for (int ni = 0; ni < 4; ++ni) cs[ni] = pC[jj * BN + ni * 16];
                asm volatile("" ::: "memory");
                if (t + 2 < 32) STAGE(t + 2, (t + 2) % 3);

                const int kb = k0base + jj * BN;
                #pragma unroll
                for (int mi = 0; mi < 4; ++mi)
                    #pragma unroll
                    for (int e = 0; e < 4; ++e) {
                        const int sI = mi * 4 + e;
                        #pragma unroll
                        for (int ni = 0; ni < 4; ++ni) {
                            float d = fmaf(-2.f, acc[mi][ni][e], cs[ni]);
                            TOP2(d, kb + ni * 16, sI);
                        }
                    }
            }
        }
    }

    // ---- merge scratch aliased over sA ----
    __syncthreads();
    char* mbase = (char*)sA;
    float (*sV1)[BM] = (float(*)[BM])(mbase);
    int   (*sI1)[BM] = (int  (*)[BM])(mbase + 1024);
    float (*sV2)[BM] = (float(*)[BM])(mbase + 2048);
    int   (*sI2)[BM] = (int  (*)[BM])(mbase + 3072);

    // butterfly lex-merge of top-2 over the 16 c-lanes
    #pragma unroll
    for (int s = 0; s < 16; ++s) {
        float a1 = rv1[s], a2 = rv2[s];
        int   b1 = (int)(pk[s] & 0xFFFFu), b2 = (int)(pk[s] >> 16);
        #pragma unroll
        for (int m = 1; m < 16; m <<= 1) {
            float w1 = __shfl_xor(a1, m), w2 = __shfl_xor(a2, m);
            int   j1 = __shfl_xor(b1, m), j2 = __shfl_xor(b2, m);
            bool lt = (w1 < a1) || (w1 == a1 && j1 < b1);
            float f1v = lt ? w1 : a1;  int g1 = lt ? j1 : b1;
            float o1 = lt ? a1 : w1;   int p1 = lt ? b1 : j1;
            float o2 = lt ? w2 : a2;   int p2 = lt ? j2 : b2;
            bool lt2 = (o1 < o2) || (o1 == o2 && p1 < p2);
            a1 = f1v; b1 = g1;
            a2 = lt2 ? o1 : o2; b2 = lt2 ? p1 : p2;
        }
        if (c == 0) {
            int row = (s >> 2) * 16 + q * 4 + (s & 3);
            sV1[wn][row] = a1; sI1[wn][row] = b1;
            sV2[wn][row] = a2; sI2[wn][row] = b2;
        }
    }
    __syncthreads();

    // merge the four column-quarters, write (v1,i1,v2,i2) per row for this j-group
    if (tid < BM) {
        float a1 = sV1[0][tid], a2 = sV2[0][tid];
        int   b1 = sI1[0][tid], b2 = sI2[0][tid];
        #pragma unroll
        for (int g = 1; g < 4; ++g) {
            float w1 = sV1[g][tid], w2 = sV2[g][tid];
            int   j1 = sI1[g][tid], j2 = sI2[g][tid];
            bool lt = (w1 < a1) || (w1 == a1 && j1 < b1);
            float f1 = lt ? w1 : a1;  int g1 = lt ? j1 : b1;
            float o1 = lt ? a1 : w1;  int p1 = lt ? b1 : j1;
            float o2 = lt ? w2 : a2;  int p2 = lt ? j2 : b2;
            bool lt2 = (o1 < o2) || (o1 == o2 && p1 < p2);
            a1 = f1; b1 = g1;
            a2 = lt2 ? o1 : o2; b2 = lt2 ? p1 : p2;
        }
        float4 outp;
        outp.x = a1;  outp.y = __int_as_float(b1);
        outp.z = a2;  outp.w = __int_as_float(b2);
        pairs[(size_t)jg * NROWS + mB * BM + tid] = outp;
    }
#undef STAGE
#undef TOP2
}

// ---------------- kernel 2: merge 4 group-top-2 pairs -> top-4 indices ----------------
__global__ __launch_bounds__(256) void merge_kernel(const float4* __restrict__ pairs,
                                                    int* __restrict__ top4) {
    const int row = blockIdx.x * 256 + threadIdx.x;
    float tv[4] = { INFINITY, INFINITY, INFINITY, INFINITY };
    int   tk[4] = { 0x7FFFFFFF, 0x7FFFFFFF, 0x7FFFFFFF, 0x7FFFFFFF };
    for (int j = 0; j < NJG; ++j) {
        float4 p = pairs[(size_t)j * NROWS + row];
        #pragma unroll
        for (int h = 0; h < 2; ++h) {
            float v = h ? p.z : p.x;
            int   k = __float_as_int(h ? p.w : p.y);
            if (v < tv[3] || (v == tv[3] && k < tk[3])) {
                tv[3] = v; tk[3] = k;
                #pragma unroll
                for (int t = 3; t > 0; --t) {
                    bool lt = (tv[t] < tv[t-1]) || (tv[t] == tv[t-1] && tk[t] < tk[t-1]);
                    if (lt) {
                        float fv = tv[t]; tv[t] = tv[t-1]; tv[t-1] = fv;
                        int   fk = tk[t]; tk[t] = tk[t-1]; tk[t-1] = fk;
                    }
                }
            }
        }
    }
    #pragma unroll
    for (int t = 0; t < 4; ++t) top4[(size_t)row * 4 + t] = tk[t];
}

// ---------------- kernel 3: rescore with exact fp32 recipe + gather + loss ----------------
__global__ __launch_bounds__(256) void rescore_kernel(const float* __restrict__ x,
                                                      const float* __restrict__ cb,
                                                      const float* __restrict__ csq,
                                                      const int* __restrict__ top4,
                                                      float* __restrict__ out,
                                                      float* __restrict__ partial) {
    __shared__ float sx[64 * 256];
    __shared__ float rv[64][4];
    __shared__ int   rk[64][4];
    __shared__ int   pick[64];
    __shared__ float sred[256];

    const int tid = threadIdx.x;
    const int rowBase = blockIdx.x * 64;
    const float4* x4 = (const float4*)x;
    const float4* c4 = (const float4*)cb;

    #pragma unroll
    for (int i = 0; i < 16; ++i) {
        int g = tid + i * 256;
        ((float4*)sx)[g] = x4[(size_t)rowBase * 64 + g];
    }
    __syncthreads();

    {
        const int r = tid >> 2, ci = tid & 3;
        const int k = top4[(size_t)(rowBase + r) * 4 + ci];
        const float4* cr = c4 + (size_t)k * 64;
        const float4* xr = (const float4*)sx + r * 64;
        float acc = 0.f;
        for (int d4 = 0; d4 < 64; ++d4) {
            float4 cv = cr[d4];
            float4 xv = xr[d4];
            acc = fmaf(xv.x, cv.x, acc);
            acc = fmaf(xv.y, cv.y, acc);
            acc = fmaf(xv.z, cv.z, acc);
            acc = fmaf(xv.w, cv.w, acc);
        }
        float cs = csq[k];
        float v = cs - 2.0f * acc;
        rv[r][ci] = v;
        rk[r][ci] = k;
    }
    __syncthreads();

    if (tid < 64) {
        float bv = rv[tid][0];
        int   bi = rk[tid][0];
        #pragma unroll
        for (int t = 1; t < 4; ++t) {
            float v = rv[tid][t];
            int  ii = rk[tid][t];
            if (v < bv || (v == bv && ii < bi)) { bv = v; bi = ii; }
        }
        pick[tid] = bi;
    }
    __syncthreads();

    float s = 0.f;
    #pragma unroll
    for (int i = 0; i < 16; ++i) {
        int g = tid + i * 256;
        int r = g >> 6, col = g & 63;
        int k = pick[r];
        float4 cv = c4[(size_t)k * 64 + col];
        float4 xv = ((const float4*)sx)[g];
        ((float4*)out)[(size_t)rowBase * 64 + g] = cv;
        float dx = cv.x - xv.x, dy = cv.y - xv.y, dz = cv.z - xv.z, dw = cv.w - xv.w;
        s += dx * dx + dy * dy + dz * dz + dw * dw;
    }
    sred[tid] = s;
    __syncthreads();
    for (int off = 128; off > 0; off >>= 1) {
        if (tid < off) sred[tid] += sred[tid + off];
        __syncthreads();
    }
    if (tid == 0) partial[blockIdx.x] = sred[0];
}

// ---------------- kernel 4: finalize loss ----------------
__global__ __launch_bounds__(256) void finalize_kernel(const float* __restrict__ partial,
                                                       float* __restrict__ loss_out) {
    __shared__ float sred[256];
    const int tid = threadIdx.x;
    float s = 0.f;
    for (int i = tid; i < 512; i += 256) s += partial[i];
    sred[tid] = s;
    __syncthreads();
    for (int off = 128; off > 0; off >>= 1) {
        if (tid < off) sred[tid] += sred[tid + off];
        __syncthreads();
    }
    if (tid == 0) loss_out[0] = sred[0] * 1.25f / 8388608.0f;
}

extern "C" void kernel_launch(void* const* d_in, const int* in_sizes, int n_in,
                              void* d_out, int out_size, void* d_ws, size_t ws_size,
                              hipStream_t stream) {
    const float* x  = (const float*)d_in[0];
    const float* cb = (const float*)d_in[1];
    float* out = (float*)d_out;

    char* ws = (char*)d_ws;
    unsigned short* B2 = (unsigned short*)ws;                          // 2 MB (pre-swizzled)
    float* csq         = (float*)(ws + 2097152);                       // 16 KB
    int*   top4        = (int*)(ws + 2097152 + 16384);                 // 512 KB
    float* partial     = (float*)(ws + 2097152 + 16384 + 524288);      // 2 KB

    // d_out scratch: pairs [0,2MB) consumed by merge; A2 [2MB,18MB) dead before rescore
    float4*         pairs = (float4*)d_out;
    unsigned short* A2    = (unsigned short*)((char*)d_out + 2097152);

    prep_kernel<<<4624, 256, 0, stream>>>(x, cb, A2, B2, csq);
    gemm_top2_kernel<<<(NROWS / BM) * NJG, 256, 0, stream>>>(A2, B2, csq, pairs);
    merge_kernel<<<NROWS / 256, 256, 0, stream>>>(pairs, top4);
    rescore_kernel<<<NROWS / 64, 256, 0, stream>>>(x, cb, csq, top4, out, partial);
    finalize_kernel<<<1, 256, 0, stream>>>(partial, out + 8388608);
}

// Round 9
// 290.599 us; speedup vs baseline: 2.3809x; 2.3809x over previous
//
#include <hip/hip_runtime.h>

#define KCODES 4096
#define NROWS  32768
#define DIM    256
#define BM     64
#define BN     128
#define NJG    4
#define NJB    (KCODES / (BN * NJG))   // 8 j-tiles per block

typedef __attribute__((ext_vector_type(8))) short  short8;
typedef __attribute__((ext_vector_type(4))) float  float4v;

__device__ inline unsigned short f2bf(float f) {
    unsigned u = __float_as_uint(f);
    unsigned r = (u >> 16) & 1u;
    return (unsigned short)((u + 0x7FFFu + r) >> 16);   // RNE
}
__device__ inline void load_lds16(const void* g, void* l) {
    __builtin_amdgcn_global_load_lds((const __attribute__((address_space(1))) void*)g,
                                     (__attribute__((address_space(3))) void*)l, 16, 0, 0);
}

// ---------------- kernel 0: fused prep ----------------
// blocks [0,4096): x -> A2 bf16, pre-swizzled K=32-chunk layout
//   A2 slot t = mB*2048 + kt*256 + r*4 + u  holds x[mB*64+r][kt*32 + ((u^((r>>1)&3))<<3) ..+8]
// blocks [4096,4608): cb -> B2 bf16, per 128-code j-tile chunks
//   B2 slot t = jt*4096 + ks*512 + r*4 + u holds cb[jt*128+r][ks*32 + ((u^((r>>1)&3))<<3) ..+8]
// blocks [4608,4624): csq (verbatim fp32 recipe)
__global__ __launch_bounds__(256) void prep_kernel(const float* __restrict__ x,
                                                   const float* __restrict__ cb,
                                                   unsigned short* __restrict__ A2,
                                                   unsigned short* __restrict__ B2,
                                                   float* __restrict__ csq) {
    const int bid = blockIdx.x, tid = threadIdx.x;
    if (bid < 4096) {
        int t = bid * 256 + tid;
        int u = t & 3, r = (t >> 2) & 63, kt = (t >> 8) & 7, mB = t >> 11;
        int klog = kt * 32 + ((u ^ ((r >> 1) & 3)) << 3);
        const float4* xs = (const float4*)(x + (size_t)(mB * 64 + r) * DIM + klog);
        float4 v0 = xs[0], v1 = xs[1];
        unsigned short h[8] = { f2bf(v0.x), f2bf(v0.y), f2bf(v0.z), f2bf(v0.w),
                                f2bf(v1.x), f2bf(v1.y), f2bf(v1.z), f2bf(v1.w) };
        ((short8*)A2)[t] = *(short8*)h;
    } else if (bid < 4608) {
        int t = (bid - 4096) * 256 + tid;
        int u = t & 3, r = (t >> 2) & 127, ks = (t >> 9) & 7, jt = t >> 12;
        int klog = ks * 32 + ((u ^ ((r >> 1) & 3)) << 3);
        const float4* cs = (const float4*)(cb + (size_t)(jt * 128 + r) * DIM + klog);
        float4 v0 = cs[0], v1 = cs[1];
        unsigned short h[8] = { f2bf(v0.x), f2bf(v0.y), f2bf(v0.z), f2bf(v0.w),
                                f2bf(v1.x), f2bf(v1.y), f2bf(v1.z), f2bf(v1.w) };
        ((short8*)B2)[t] = *(short8*)h;
    } else {
        int code = (bid - 4608) * 256 + tid;
        const float4* row = (const float4*)(cb + (size_t)code * DIM);
        float s = 0.f;
        #pragma unroll 8
        for (int i = 0; i < DIM / 4; ++i) {
            float4 v = row[i];
            s += v.x * v.x + v.y * v.y + v.z * v.z + v.w * v.w;
        }
        csq[code] = s;
    }
}

// ---------------- kernel 1: K=256 bf16 GEMM, tri-buffered B, 1 barrier/step ----------------
// BM=64 (sA 32 KB, DMA-staged), BN=128 across 4 waves (wave tile 64x32, acc[4][2]=32 regs
// -> live set ~125, fits the allocator's 132 budget under __launch_bounds__(256) [R5/R8 ledger]).
// 64 steps of K=32; stage(t+2) after bar(t); counted vmcnt(2). LDS 32+24=56 KB -> 2 blocks/CU.
// grid = 2048: jg=(h>>3)&3, mB=(h&7)|((h>>5)<<3)  (4 same-mB jg-blocks share an XCD L2)
__global__ __launch_bounds__(256) void gemm_top2_kernel(const unsigned short* __restrict__ A2,
                                                        const unsigned short* __restrict__ B2,
                                                        const float* __restrict__ csq,
                                                        float4* __restrict__ pairs) {
    __shared__ unsigned short sA[2048 * 8];     // 32 KB: [kt][r][u] 16B slots
    __shared__ unsigned short sB[3][512 * 8];   // 3 x 8 KB: [r][u] 16B slots

    const int tid = threadIdx.x;
    const int lane = tid & 63, wn = tid >> 6;
    const int c = lane & 15, q = lane >> 4;
    const int h  = blockIdx.x;
    const int jg = (h >> 3) & 3;
    const int mB = (h & 7) | ((h >> 5) << 3);

    // lane-constant swizzled byte offset within any 1 KB row-16 group
    const int u = q ^ ((c >> 1) & 3);
    const int laneOff = c * 64 + u * 16;
    const char* sAc = (const char*)sA;

    // ---- stage A: 8 x 16B DMA per thread from pre-swizzled A2 ----
    {
        const unsigned short* Ag = A2 + (size_t)mB * 2048 * 8;
        #pragma unroll
        for (int i = 0; i < 8; ++i)
            load_lds16(Ag + (size_t)(i * 256 + tid) * 8, &sA[(size_t)(i * 256 + tid) * 8]);
    }

#define STAGE(T, BUF) do {                                                              \
        const unsigned short* gb = B2 +                                                 \
            (size_t)((jg * NJB + ((T) >> 3)) * 8 + ((T) & 7)) * 4096;                   \
        load_lds16(gb + (size_t)tid * 8,         &sB[BUF][(size_t)tid * 8]);            \
        load_lds16(gb + (size_t)(256 + tid) * 8, &sB[BUF][(size_t)(256 + tid) * 8]);    \
    } while (0)

#define TOP2(D, K, S) do {                                       \
        bool f1 = (D) < rv1[S];                                  \
        bool f2 = (D) < rv2[S];                                  \
        unsigned p = pk[S];                                      \
        pk[S]  = f1 ? ((p << 16) | (unsigned)(K))                \
                    : (f2 ? (((unsigned)(K) << 16) | (p & 0xFFFFu)) : p); \
        rv2[S] = f1 ? rv1[S] : (f2 ? (D) : rv2[S]);              \
        rv1[S] = f1 ? (D) : rv1[S];                              \
    } while (0)

    float rv1[16], rv2[16]; unsigned pk[16];
    #pragma unroll
    for (int s = 0; s < 16; ++s) { rv1[s] = INFINITY; rv2[s] = INFINITY; pk[s] = 0xFFFFFFFFu; }

    const float* pC = csq + jg * (NJB * BN) + wn * 32 + c;
    const int k0base = jg * (NJB * BN) + wn * 32 + c;

    // ---- prologue: A DMA (8 loads) + first two B chunks (2x2 loads) in flight ----
    STAGE(0, 0);
    STAGE(1, 1);

    #pragma unroll
    for (int jj = 0; jj < NJB; ++jj) {
        float4v acc[4][2];
        #pragma unroll
        for (int mi = 0; mi < 4; ++mi)
            #pragma unroll
            for (int ni = 0; ni < 2; ++ni)
                #pragma unroll
                for (int e = 0; e < 4; ++e) acc[mi][ni][e] = 0.f;

        #pragma unroll
        for (int kt = 0; kt < 8; ++kt) {
            const int t = jj * 8 + kt;
            // counted wait: chunk t landed (A too, at t=0); stage(t+1)'s 2 loads stay in flight
            if (t == 63) asm volatile("s_waitcnt vmcnt(0)" ::: "memory");
            else         asm volatile("s_waitcnt vmcnt(2)" ::: "memory");
            __builtin_amdgcn_s_barrier();
            asm volatile("" ::: "memory");

            if (kt != 7 && t + 2 < 64) STAGE(t + 2, (t + 2) % 3);

            const char* bufp = (const char*)sB[t % 3];
            short8 aF[4], bF[2];
            #pragma unroll
            for (int mi = 0; mi < 4; ++mi)
                aF[mi] = *(const short8*)(sAc + kt * 4096 + mi * 1024 + laneOff);
            #pragma unroll
            for (int ni = 0; ni < 2; ++ni)
                bF[ni] = *(const short8*)(bufp + wn * 2048 + ni * 1024 + laneOff);
            #pragma unroll
            for (int mi = 0; mi < 4; ++mi)
                #pragma unroll
                for (int ni = 0; ni < 2; ++ni)
                    acc[mi][ni] = __builtin_amdgcn_mfma_f32_16x16x32_bf16(aF[mi], bF[ni], acc[mi][ni], 0, 0, 0);

            if (kt == 7) {
                // epilogue: csq first, THEN the deferred stage (so the compiler's
                // csq-wait leaves the stage loads in flight, not a drain)
                float cs0 = pC[jj * BN];
                float cs1 = pC[jj * BN + 16];
                asm volatile("" ::: "memory");
                if (t + 2 < 64) STAGE(t + 2, (t + 2) % 3);

                const int kb = k0base + jj * BN;
                #pragma unroll
                for (int mi = 0; mi < 4; ++mi)
                    #pragma unroll
                    for (int e = 0; e < 4; ++e) {
                        const int sI = mi * 4 + e;
                        float d0 = fmaf(-2.f, acc[mi][0][e], cs0);
                        TOP2(d0, kb, sI);
                        float d1 = fmaf(-2.f, acc[mi][1][e], cs1);
                        TOP2(d1, kb + 16, sI);
                    }
            }
        }
    }

    // ---- merge scratch aliased over sA ----
    __syncthreads();
    char* mbase = (char*)sA;
    float (*sV1)[BM] = (float(*)[BM])(mbase);
    int   (*sI1)[BM] = (int  (*)[BM])(mbase + 1024);
    float (*sV2)[BM] = (float(*)[BM])(mbase + 2048);
    int   (*sI2)[BM] = (int  (*)[BM])(mbase + 3072);

    // butterfly lex-merge of top-2 over the 16 c-lanes
    #pragma unroll
    for (int s = 0; s < 16; ++s) {
        float a1 = rv1[s], a2 = rv2[s];
        int   b1 = (int)(pk[s] & 0xFFFFu), b2 = (int)(pk[s] >> 16);
        #pragma unroll
        for (int m = 1; m < 16; m <<= 1) {
            float w1 = __shfl_xor(a1, m), w2 = __shfl_xor(a2, m);
            int   j1 = __shfl_xor(b1, m), j2 = __shfl_xor(b2, m);
            bool lt = (w1 < a1) || (w1 == a1 && j1 < b1);
            float f1v = lt ? w1 : a1;  int g1 = lt ? j1 : b1;
            float o1 = lt ? a1 : w1;   int p1 = lt ? b1 : j1;
            float o2 = lt ? w2 : a2;   int p2 = lt ? j2 : b2;
            bool lt2 = (o1 < o2) || (o1 == o2 && p1 < p2);
            a1 = f1v; b1 = g1;
            a2 = lt2 ? o1 : o2; b2 = lt2 ? p1 : p2;
        }
        if (c == 0) {
            int row = (s >> 2) * 16 + q * 4 + (s & 3);
            sV1[wn][row] = a1; sI1[wn][row] = b1;
            sV2[wn][row] = a2; sI2[wn][row] = b2;
        }
    }
    __syncthreads();

    // merge the four column-quarters, write (v1,i1,v2,i2) per row for this j-group
    if (tid < BM) {
        float a1 = sV1[0][tid], a2 = sV2[0][tid];
        int   b1 = sI1[0][tid], b2 = sI2[0][tid];
        #pragma unroll
        for (int g = 1; g < 4; ++g) {
            float w1 = sV1[g][tid], w2 = sV2[g][tid];
            int   j1 = sI1[g][tid], j2 = sI2[g][tid];
            bool lt = (w1 < a1) || (w1 == a1 && j1 < b1);
            float f1 = lt ? w1 : a1;  int g1 = lt ? j1 : b1;
            float o1 = lt ? a1 : w1;  int p1 = lt ? b1 : j1;
            float o2 = lt ? w2 : a2;  int p2 = lt ? j2 : b2;
            bool lt2 = (o1 < o2) || (o1 == o2 && p1 < p2);
            a1 = f1; b1 = g1;
            a2 = lt2 ? o1 : o2; b2 = lt2 ? p1 : p2;
        }
        float4 outp;
        outp.x = a1;  outp.y = __int_as_float(b1);
        outp.z = a2;  outp.w = __int_as_float(b2);
        pairs[(size_t)jg * NROWS + mB * BM + tid] = outp;
    }
#undef STAGE
#undef TOP2
}

// ---------------- kernel 2: merge 4 group-top-2 pairs -> top-4 indices ----------------
__global__ __launch_bounds__(256) void merge_kernel(const float4* __restrict__ pairs,
                                                    int* __restrict__ top4) {
    const int row = blockIdx.x * 256 + threadIdx.x;
    float tv[4] = { INFINITY, INFINITY, INFINITY, INFINITY };
    int   tk[4] = { 0x7FFFFFFF, 0x7FFFFFFF, 0x7FFFFFFF, 0x7FFFFFFF };
    for (int j = 0; j < NJG; ++j) {
        float4 p = pairs[(size_t)j * NROWS + row];
        #pragma unroll
        for (int h = 0; h < 2; ++h) {
            float v = h ? p.z : p.x;
            int   k = __float_as_int(h ? p.w : p.y);
            if (v < tv[3] || (v == tv[3] && k < tk[3])) {
                tv[3] = v; tk[3] = k;
                #pragma unroll
                for (int t = 3; t > 0; --t) {
                    bool lt = (tv[t] < tv[t-1]) || (tv[t] == tv[t-1] && tk[t] < tk[t-1]);
                    if (lt) {
                        float fv = tv[t]; tv[t] = tv[t-1]; tv[t-1] = fv;
                        int   fk = tk[t]; tk[t] = tk[t-1]; tk[t-1] = fk;
                    }
                }
            }
        }
    }
    #pragma unroll
    for (int t = 0; t < 4; ++t) top4[(size_t)row * 4 + t] = tk[t];
}

// ---------------- kernel 3: rescore with exact fp32 recipe + gather + loss ----------------
__global__ __launch_bounds__(256) void rescore_kernel(const float* __restrict__ x,
                                                      const float* __restrict__ cb,
                                                      const float* __restrict__ csq,
                                                      const int* __restrict__ top4,
                                                      float* __restrict__ out,
                                                      float* __restrict__ partial) {
    __shared__ float sx[64 * 256];
    __shared__ float rv[64][4];
    __shared__ int   rk[64][4];
    __shared__ int   pick[64];
    __shared__ float sred[256];

    const int tid = threadIdx.x;
    const int rowBase = blockIdx.x * 64;
    const float4* x4 = (const float4*)x;
    const float4* c4 = (const float4*)cb;

    #pragma unroll
    for (int i = 0; i < 16; ++i) {
        int g = tid + i * 256;
        ((float4*)sx)[g] = x4[(size_t)rowBase * 64 + g];
    }
    __syncthreads();

    {
        const int r = tid >> 2, ci = tid & 3;
        const int k = top4[(size_t)(rowBase + r) * 4 + ci];
        const float4* cr = c4 + (size_t)k * 64;
        const float4* xr = (const float4*)sx + r * 64;
        float acc = 0.f;
        for (int d4 = 0; d4 < 64; ++d4) {
            float4 cv = cr[d4];
            float4 xv = xr[d4];
            acc = fmaf(xv.x, cv.x, acc);
            acc = fmaf(xv.y, cv.y, acc);
            acc = fmaf(xv.z, cv.z, acc);
            acc = fmaf(xv.w, cv.w, acc);
        }
        float cs = csq[k];
        float v = cs - 2.0f * acc;
        rv[r][ci] = v;
        rk[r][ci] = k;
    }
    __syncthreads();

    if (tid < 64) {
        float bv = rv[tid][0];
        int   bi = rk[tid][0];
        #pragma unroll
        for (int t = 1; t < 4; ++t) {
            float v = rv[tid][t];
            int  ii = rk[tid][t];
            if (v < bv || (v == bv && ii < bi)) { bv = v; bi = ii; }
        }
        pick[tid] = bi;
    }
    __syncthreads();

    float s = 0.f;
    #pragma unroll
    for (int i = 0; i < 16; ++i) {
        int g = tid + i * 256;
        int r = g >> 6, col = g & 63;
        int k = pick[r];
        float4 cv = c4[(size_t)k * 64 + col];
        float4 xv = ((const float4*)sx)[g];
        ((float4*)out)[(size_t)rowBase * 64 + g] = cv;
        float dx = cv.x - xv.x, dy = cv.y - xv.y, dz = cv.z - xv.z, dw = cv.w - xv.w;
        s += dx * dx + dy * dy + dz * dz + dw * dw;
    }
    sred[tid] = s;
    __syncthreads();
    for (int off = 128; off > 0; off >>= 1) {
        if (tid < off) sred[tid] += sred[tid + off];
        __syncthreads();
    }
    if (tid == 0) partial[blockIdx.x] = sred[0];
}

// ---------------- kernel 4: finalize loss ----------------
__global__ __launch_bounds__(256) void finalize_kernel(const float* __restrict__ partial,
                                                       float* __restrict__ loss_out) {
    __shared__ float sred[256];
    const int tid = threadIdx.x;
    float s = 0.f;
    for (int i = tid; i < 512; i += 256) s += partial[i];
    sred[tid] = s;
    __syncthreads();
    for (int off = 128; off > 0; off >>= 1) {
        if (tid < off) sred[tid] += sred[tid + off];
        __syncthreads();
    }
    if (tid == 0) loss_out[0] = sred[0] * 1.25f / 8388608.0f;
}

extern "C" void kernel_launch(void* const* d_in, const int* in_sizes, int n_in,
                              void* d_out, int out_size, void* d_ws, size_t ws_size,
                              hipStream_t stream) {
    const float* x  = (const float*)d_in[0];
    const float* cb = (const float*)d_in[1];
    float* out = (float*)d_out;

    char* ws = (char*)d_ws;
    unsigned short* B2 = (unsigned short*)ws;                          // 2 MB (pre-swizzled)
    float* csq         = (float*)(ws + 2097152);                       // 16 KB
    int*   top4        = (int*)(ws + 2097152 + 16384);                 // 512 KB
    float* partial     = (float*)(ws + 2097152 + 16384 + 524288);      // 2 KB

    // d_out scratch: pairs [0,2MB) consumed by merge; A2 [2MB,18MB) dead before rescore
    float4*         pairs = (float4*)d_out;
    unsigned short* A2    = (unsigned short*)((char*)d_out + 2097152);

    prep_kernel<<<4624, 256, 0, stream>>>(x, cb, A2, B2, csq);
    gemm_top2_kernel<<<(NROWS / BM) * NJG, 256, 0, stream>>>(A2, B2, csq, pairs);
    merge_kernel<<<NROWS / 256, 256, 0, stream>>>(pairs, top4);
    rescore_kernel<<<NROWS / 64, 256, 0, stream>>>(x, cb, csq, top4, out, partial);
    finalize_kernel<<<1, 256, 0, stream>>>(partial, out + 8388608);
}